// Round 3
// baseline (585.615 us; speedup 1.0000x reference)
//
#include <hip/hip_runtime.h>
#include <hip/hip_bf16.h>

#define T_LEN 2048
#define B_SZ  2048
#define H_SZ  8
#define L_SZ  4

// tanh(x) = 1 - 2/(exp(2x)+1)  (identical numerics to round-2 pass)
__device__ __forceinline__ float tanh_fast(float x) {
    float e = __expf(2.0f * x);
    float r = __builtin_amdgcn_rcpf(e + 1.0f);
    return __builtin_fmaf(-2.0f, r, 1.0f);
}

// rotate-by-(CTRL-0x120) within each 16-lane row; with the 8-periodic lane
// pattern this is rotation within the 8 hidden units. Compiler-known DPP
// (hazard-safe), all lanes active -> bound_ctrl irrelevant.
template<int CTRL>
__device__ __forceinline__ float rot_dpp(float v) {
    return __int_as_float(
        __builtin_amdgcn_update_dpp(0, __float_as_int(v), CTRL, 0xF, 0xF, false));
}

#define ROT8(d, s) \
    d[0] = (s);               d[1] = rot_dpp<0x121>(s); \
    d[2] = rot_dpp<0x122>(s); d[3] = rot_dpp<0x123>(s); \
    d[4] = rot_dpp<0x124>(s); d[5] = rot_dpp<0x125>(s); \
    d[6] = rot_dpp<0x126>(s); d[7] = rot_dpp<0x127>(s);

// serial 8-deep FMA chain (intended: dep path ~32cy, 8 such chains overlap)
__device__ __forceinline__ float dot8(const float* w, const float* r, float base) {
    float a = __builtin_fmaf(w[0], r[0], base);
    #pragma unroll
    for (int s = 1; s < 8; ++s) a = __builtin_fmaf(w[s], r[s], a);
    return a;
}

__global__ __launch_bounds__(64, 1)
void rnn_dpp(const float* __restrict__ x,
             const float* __restrict__ h0_in,
             const float* __restrict__ w_ih0,
             const float* __restrict__ w_ih,
             const float* __restrict__ w_hh,
             const float* __restrict__ b_ih,
             const float* __restrict__ b_hh,
             const float* __restrict__ w_lin,
             const float* __restrict__ b_lin,
             float* __restrict__ out)
{
    __shared__ __align__(16) float xs[T_LEN + 8];

    const int lane = threadIdx.x;
    const int u    = lane & 7;          // hidden unit; every lane holds ALL 4 layers

    for (int i = lane; i < T_LEN; i += 64)
        xs[i] = x[(size_t)i * B_SZ + (B_SZ - 1)];
    if (lane < 8) xs[T_LEN + lane] = 0.0f;
    __syncthreads();

    // runtime DPP-direction probe: after ror:s, does this lane see unit (u+s)&7
    // or (u-s)&7 ?  Select pre-permuted weights accordingly (both are correct).
    int rot1 = __builtin_amdgcn_update_dpp(0, lane, 0x121, 0xF, 0xF, false);
    const bool plus = ((rot1 & 15) == ((lane + 1) & 15));

    float whh0p[8], whh1p[8], whh2p[8], whh3p[8];
    float wih1p[8], wih2p[8], wih3p[8], wlinp[8];
    #pragma unroll
    for (int s = 0; s < 8; ++s) {
        int j = plus ? ((u + s) & 7) : ((u - s) & 7);
        whh0p[s] = w_hh[(0 * H_SZ + u) * H_SZ + j];
        whh1p[s] = w_hh[(1 * H_SZ + u) * H_SZ + j];
        whh2p[s] = w_hh[(2 * H_SZ + u) * H_SZ + j];
        whh3p[s] = w_hh[(3 * H_SZ + u) * H_SZ + j];
        wih1p[s] = w_ih[(0 * H_SZ + u) * H_SZ + j];
        wih2p[s] = w_ih[(1 * H_SZ + u) * H_SZ + j];
        wih3p[s] = w_ih[(2 * H_SZ + u) * H_SZ + j];
        wlinp[s] = w_lin[j];
    }
    const float wx    = w_ih0[u];
    const float bias0 = b_ih[0 * H_SZ + u] + b_hh[0 * H_SZ + u];
    const float bias1 = b_ih[1 * H_SZ + u] + b_hh[1 * H_SZ + u];
    const float bias2 = b_ih[2 * H_SZ + u] + b_hh[2 * H_SZ + u];
    const float bias3 = b_ih[3 * H_SZ + u] + b_hh[3 * H_SZ + u];
    const float bl    = b_lin[0];

    float h0 = h0_in[((size_t)0 * B_SZ + (B_SZ - 1)) * H_SZ + u];
    float h1 = h0_in[((size_t)1 * B_SZ + (B_SZ - 1)) * H_SZ + u];
    float h2 = h0_in[((size_t)2 * B_SZ + (B_SZ - 1)) * H_SZ + u];
    float h3 = h0_in[((size_t)3 * B_SZ + (B_SZ - 1)) * H_SZ + u];

    // ---- warm-up ticks k=0..3 (layer l live from tick l) ----
    for (int k = 0; k < L_SZ; ++k) {
        float r0[8], r1[8], r2[8], r3[8];
        ROT8(r0, h0) ROT8(r1, h1) ROT8(r2, h2) ROT8(r3, h3)
        float c0 = __builtin_fmaf(wx, xs[k], bias0);
        float a0 = dot8(whh0p, r0, c0);
        float a1 = dot8(whh1p, r1, bias1) + dot8(wih1p, r0, 0.0f);
        float a2 = dot8(whh2p, r2, bias2) + dot8(wih2p, r1, 0.0f);
        float a3 = dot8(whh3p, r3, bias3) + dot8(wih3p, r2, 0.0f);
        h0 = tanh_fast(a0);
        h1 = (k >= 1) ? tanh_fast(a1) : h1;
        h2 = (k >= 2) ? tanh_fast(a2) : h2;
        h3 = (k >= 3) ? tanh_fast(a3) : h3;
    }

    // ---- main loop: tick k rotates state S(k-1); h3 of S(k-1) = h_3(k-4)
    //      -> emits out[k-4]. k = 4..2051, 4 ticks per block, 512 blocks. ----
    const float4* xsv  = (const float4*)xs;
    float4        xcur = xsv[1];          // xs[4..7]
    float*        outp = out;

    for (int kb = 4; kb < T_LEN + L_SZ; kb += 4) {
        float4 xnxt = xsv[(kb >> 2) + 1]; // prefetch xs[kb+4..kb+7] (next block)
        float ov[4];
        float cc[4] = { __builtin_fmaf(wx, xcur.x, bias0),
                        __builtin_fmaf(wx, xcur.y, bias0),
                        __builtin_fmaf(wx, xcur.z, bias0),
                        __builtin_fmaf(wx, xcur.w, bias0) };
        #pragma unroll
        for (int t = 0; t < 4; ++t) {
            float r0[8], r1[8], r2[8], r3[8];
            ROT8(r0, h0) ROT8(r1, h1) ROT8(r2, h2) ROT8(r3, h3)
            float a0 = dot8(whh0p, r0, cc[t]);
            float a1 = dot8(whh1p, r1, bias1) + dot8(wih1p, r0, 0.0f);
            float a2 = dot8(whh2p, r2, bias2) + dot8(wih2p, r1, 0.0f);
            float a3 = dot8(whh3p, r3, bias3) + dot8(wih3p, r2, 0.0f);
            ov[t] = dot8(wlinp, r3, 0.0f) + bl;   // uses OLD h3 = h_3(kb+t-4)
            h0 = tanh_fast(a0);
            h1 = tanh_fast(a1);
            h2 = tanh_fast(a2);
            h3 = tanh_fast(a3);
        }
        // all 64 lanes hold identical values; same-address store coalesces
        *(float4*)outp = make_float4(ov[0], ov[1], ov[2], ov[3]);
        outp += 4;
        xcur = xnxt;
    }
}

extern "C" void kernel_launch(void* const* d_in, const int* in_sizes, int n_in,
                              void* d_out, int out_size, void* d_ws, size_t ws_size,
                              hipStream_t stream) {
    const float* x     = (const float*)d_in[0];
    const float* h0    = (const float*)d_in[1];
    const float* w_ih0 = (const float*)d_in[2];
    const float* w_ih  = (const float*)d_in[3];
    const float* w_hh  = (const float*)d_in[4];
    const float* b_ih  = (const float*)d_in[5];
    const float* b_hh  = (const float*)d_in[6];
    const float* w_lin = (const float*)d_in[7];
    const float* b_lin = (const float*)d_in[8];
    float* out = (float*)d_out;

    rnn_dpp<<<dim3(1), dim3(64), 0, stream>>>(
        x, h0, w_ih0, w_ih, w_hh, b_ih, b_hh, w_lin, b_lin, out);
}

// Round 5
// 261.410 us; speedup vs baseline: 2.2402x; 2.2402x over previous
//
#include <hip/hip_runtime.h>

#define T_LEN 2048
#define B_SZ  2048
#define H_SZ  8
#define WARM  12      // layer l live from tick 3l; outputs from tick 12
#define XS_N  2064

// tanh(x) = 1 - 2/(exp(2x)+1)  (absmax 0.0 in rounds 2-3)
__device__ __forceinline__ float tanh_fast(float x) {
    float e = __expf(2.0f * x);
    float r = __builtin_amdgcn_rcpf(e + 1.0f);
    return __builtin_fmaf(-2.0f, r, 1.0f);
}

// row_ror:(CTRL-0x120) within 16-lane rows; 8-periodic data -> rotate mod 8
template<int CTRL>
__device__ __forceinline__ float rot_dpp(float v) {
    return __int_as_float(
        __builtin_amdgcn_update_dpp(0, __float_as_int(v), CTRL, 0xF, 0xF, false));
}

__global__ __launch_bounds__(64, 1)
void rnn_bperm(const float* __restrict__ x,
               const float* __restrict__ h0_in,
               const float* __restrict__ w_ih0,
               const float* __restrict__ w_ih,
               const float* __restrict__ w_hh,
               const float* __restrict__ b_ih,
               const float* __restrict__ b_hh,
               const float* __restrict__ w_lin,
               const float* __restrict__ b_lin,
               float* __restrict__ out)
{
    __shared__ __align__(16) float xs[XS_N];

    const int lane = threadIdx.x;
    const int u    = lane & 7;          // hidden unit (each 16-row holds units 0-7 twice)
    const int l    = lane >> 4;         // row = layer
    const int lp   = (l + 3) & 3;       // import source row (row0 <- row3 = output)
    const int bidx = ((lp << 4) | (lane & 15)) << 2;   // ds_bpermute byte index

    for (int i = lane; i < XS_N; i += 64) xs[i] = 0.0f;
    __syncthreads();
    for (int i = lane; i < T_LEN; i += 64) xs[i] = x[(size_t)i * B_SZ + (B_SZ - 1)];
    __syncthreads();   // xs is read-only after this point

    // DPP direction probe (HW-verified round 3)
    int rot1 = __builtin_amdgcn_update_dpp(0, lane, 0x121, 0xF, 0xF, false);
    const bool plus = ((rot1 & 15) == ((lane + 1) & 15));

    // whh: own recurrent dot.  wexp: dot EXPORTED to row l+1
    // (w_ih[l] for l<3; w_lin for row 3 -> the output scalar).
    float whh_p[8], wexp_p[8];
    #pragma unroll
    for (int s = 0; s < 8; ++s) {
        int j = plus ? ((u + s) & 7) : ((u - s) & 7);
        whh_p[s]  = w_hh[(l * H_SZ + u) * H_SZ + j];
        wexp_p[s] = (l < 3) ? w_ih[(l * H_SZ + u) * H_SZ + j] : w_lin[j];
    }
    const float bias = b_ih[l * H_SZ + u] + b_hh[l * H_SZ + u];
    const float wx   = (l == 0) ? w_ih0[u] : 0.0f;
    const float selw = (l == 0) ? 0.0f : 1.0f;   // row0: import is the OUTPUT, not a tanh term
    const float bl   = b_lin[0];

    float h   = h0_in[((size_t)l * B_SZ + (B_SZ - 1)) * H_SZ + u];
    float ipA = 0.0f, ipB = 0.0f;   // import pipeline: issued at tick k -> consumed at k+2

    // One pipeline tick.  ip: slot (k&1).  Order: consume import, compute,
    // then refill slot with the bpermute issued THIS tick (consumed at k+2).
    auto tick = [&](float& ip, float xbase, float& outv) -> float {
        float r1 = rot_dpp<0x121>(h), r2 = rot_dpp<0x122>(h),
              r3 = rot_dpp<0x123>(h), r4 = rot_dpp<0x124>(h),
              r5 = rot_dpp<0x125>(h), r6 = rot_dpp<0x126>(h),
              r7 = rot_dpp<0x127>(h);
        // export dot: serial chain (2 ticks of slack -> depth irrelevant)
        float e = wexp_p[0] * h;
        e = __builtin_fmaf(wexp_p[1], r1, e);
        e = __builtin_fmaf(wexp_p[2], r2, e);
        e = __builtin_fmaf(wexp_p[3], r3, e);
        e = __builtin_fmaf(wexp_p[4], r4, e);
        e = __builtin_fmaf(wexp_p[5], r5, e);
        e = __builtin_fmaf(wexp_p[6], r6, e);
        e = __builtin_fmaf(wexp_p[7], r7, e);
        // own dot: balanced tree (on the tanh critical path)
        float t0 = __builtin_fmaf(whh_p[0], h,  whh_p[1] * r1);
        float t1 = __builtin_fmaf(whh_p[2], r2, whh_p[3] * r3);
        float t2 = __builtin_fmaf(whh_p[4], r4, whh_p[5] * r5);
        float t3 = __builtin_fmaf(whh_p[6], r6, whh_p[7] * r7);
        float own = (t0 + t1) + (t2 + t3);
        outv = ip;                                   // row0 lane0: out[k-12] (pre-bias)
        float aa = __builtin_fmaf(selw, ip, xbase + own);
        ip = __int_as_float(__builtin_amdgcn_ds_bpermute(bidx, __float_as_int(e)));
        return tanh_fast(aa);
    };

    // ---- warm-up ticks 0..11: layer l's h updates only from tick 3l ----
    #pragma unroll
    for (int k = 0; k < WARM; ++k) {
        float dummy;
        float xbase = __builtin_fmaf(wx, xs[k], bias);
        float hn = (k & 1) ? tick(ipB, xbase, dummy) : tick(ipA, xbase, dummy);
        h = (k >= 3 * l) ? hn : h;
    }

    // ---- main: ticks 12..2059, tick k emits out[k-12] via row0's import ----
    const float4* xsv = (const float4*)xs;
    for (int kb = WARM; kb <= 2056; kb += 4) {
        float4 xq = xsv[kb >> 2];   // xs[kb..kb+3]; zero-padded past T_LEN
        float ov0, ov1, ov2, ov3;
        h = tick(ipA, __builtin_fmaf(wx, xq.x, bias), ov0);
        h = tick(ipB, __builtin_fmaf(wx, xq.y, bias), ov1);
        h = tick(ipA, __builtin_fmaf(wx, xq.z, bias), ov2);
        h = tick(ipB, __builtin_fmaf(wx, xq.w, bias), ov3);
        if (lane == 0)
            *(float4*)(out + (kb - WARM)) =
                make_float4(ov0 + bl, ov1 + bl, ov2 + bl, ov3 + bl);
    }
}

extern "C" void kernel_launch(void* const* d_in, const int* in_sizes, int n_in,
                              void* d_out, int out_size, void* d_ws, size_t ws_size,
                              hipStream_t stream) {
    const float* x     = (const float*)d_in[0];
    const float* h0    = (const float*)d_in[1];
    const float* w_ih0 = (const float*)d_in[2];
    const float* w_ih  = (const float*)d_in[3];
    const float* w_hh  = (const float*)d_in[4];
    const float* b_ih  = (const float*)d_in[5];
    const float* b_hh  = (const float*)d_in[6];
    const float* w_lin = (const float*)d_in[7];
    const float* b_lin = (const float*)d_in[8];
    float* out = (float*)d_out;

    rnn_bperm<<<dim3(1), dim3(64), 0, stream>>>(
        x, h0, w_ih0, w_ih, w_hh, b_ih, b_hh, w_lin, b_lin, out);
}

// Round 6
// 231.807 us; speedup vs baseline: 2.5263x; 1.1277x over previous
//
#include <hip/hip_runtime.h>

#define T_LEN 2048
#define B_SZ  2048
#define H_SZ  8
#define WARM  12      // layer l live from tick 3l; outputs from tick 12
#define XS_N  2064

#if __has_builtin(__builtin_amdgcn_exp2f)
  #define EXP2F(x) __builtin_amdgcn_exp2f(x)
#else
  #define EXP2F(x) __expf(0.69314718055994531f * (x))
#endif

// row_ror:(CTRL-0x120) within 16-lane rows; 8-periodic data -> rotate mod 8
template<int CTRL>
__device__ __forceinline__ float rot_dpp(float v) {
    return __int_as_float(
        __builtin_amdgcn_update_dpp(0, __float_as_int(v), CTRL, 0xF, 0xF, false));
}

__global__ __launch_bounds__(64, 1)
void rnn_sig(const float* __restrict__ x,
             const float* __restrict__ h0_in,
             const float* __restrict__ w_ih0,
             const float* __restrict__ w_ih,
             const float* __restrict__ w_hh,
             const float* __restrict__ b_ih,
             const float* __restrict__ b_hh,
             const float* __restrict__ w_lin,
             const float* __restrict__ b_lin,
             float* __restrict__ out)
{
    __shared__ __align__(16) float xs[XS_N];

    const int lane = threadIdx.x;
    const int u    = lane & 7;            // hidden unit
    const int l    = lane >> 4;           // row = layer
    const int grpB = (lane >> 3) & 1;     // 0: own-dot lanes, 1: export-dot lanes
    const int lp   = (l + 3) & 3;         // import source row (row0 <- row3 = output)
    const int bidx = (((lp << 4) | 8 | u)) << 2;   // pull from source row's B-half

    for (int i = lane; i < XS_N; i += 64) xs[i] = 0.0f;
    __syncthreads();
    for (int i = lane; i < T_LEN; i += 64) xs[i] = x[(size_t)i * B_SZ + (B_SZ - 1)];
    __syncthreads();

    // DPP direction probe (HW-verified round 3)
    int rot1 = __builtin_amdgcn_update_dpp(0, lane, 0x121, 0xF, 0xF, false);
    const bool plus = ((rot1 & 15) == ((lane + 1) & 15));

    const float C  = 2.0f * 1.4426950408889634f;   // 2*log2(e): h=tanh(a) -> r=rcp(exp2(C*a)+1)
    const float m2C = -2.0f * C;

    // rowsums (fold "Sum w*h = rowsum - 2 Sum w*r" constants into bias)
    float whh_rs = 0.0f, wih_rs = 0.0f, wlin_rs = 0.0f;
    #pragma unroll
    for (int j = 0; j < 8; ++j) {
        whh_rs += w_hh[(l * H_SZ + u) * H_SZ + j];
        if (l > 0) wih_rs += w_ih[((l - 1) * H_SZ + u) * H_SZ + j];
        wlin_rs += w_lin[j];
    }
    const float bl_tot = wlin_rs + b_lin[0];

    // per-lane dot weights: A-half = own recurrence (-2C*whh), B-half = export
    // (-2C*w_ih[l] for l<3 ; -2*w_lin for l==3 -> raw output scale)
    float wsel[8];
    #pragma unroll
    for (int s = 0; s < 8; ++s) {
        int j = plus ? ((u + s) & 7) : ((u - s) & 7);
        float whh2  = m2C * w_hh[(l * H_SZ + u) * H_SZ + j];
        float wexp2 = (l < 3) ? m2C * w_ih[(l * H_SZ + u) * H_SZ + j]
                              : -2.0f * w_lin[j];
        wsel[s] = grpB ? wexp2 : whh2;
    }
    const float tbase  = (grpB && l == 3) ? bl_tot : 0.0f;   // output bias rides the export
    const float xconst = C * (b_ih[l * H_SZ + u] + b_hh[l * H_SZ + u]
                              + whh_rs + ((l > 0) ? wih_rs : 0.0f));
    const float wx2 = (l == 0) ? C * w_ih0[u] : 0.0f;
    const float sel = (l == 0) ? 0.0f : 1.0f;   // row0's import is the OUTPUT, not a y-term

    // state r = (1 - h)/2
    float r = __builtin_fmaf(-0.5f, h0_in[((size_t)l * B_SZ + (B_SZ - 1)) * H_SZ + u], 0.5f);
    float ipA = 0.0f, ipB = 0.0f;   // import pipeline: issued at tick k -> consumed at k+2

    auto tick = [&](float& ip, float xb, float& outv) -> float {
        float r1 = rot_dpp<0x121>(r), r2 = rot_dpp<0x122>(r),
              r3 = rot_dpp<0x123>(r), r4 = rot_dpp<0x124>(r),
              r5 = rot_dpp<0x125>(r), r6 = rot_dpp<0x126>(r),
              r7 = rot_dpp<0x127>(r);
        float t0 = __builtin_fmaf(wsel[0], r,  tbase);
        t0 = __builtin_fmaf(wsel[1], r1, t0);
        float t1 = wsel[2] * r2; t1 = __builtin_fmaf(wsel[3], r3, t1);
        float t2 = wsel[4] * r4; t2 = __builtin_fmaf(wsel[5], r5, t2);
        float t3 = wsel[6] * r6; t3 = __builtin_fmaf(wsel[7], r7, t3);
        float S  = (t0 + t1) + (t2 + t3);     // A lanes: own-sum, B lanes: export E
        float sw = rot_dpp<0x128>(S);          // swap halves (ror:8, direction-agnostic)
        float own = grpB ? sw : S;             // own-sum in all 16 lanes
        outv = ip;                             // row0: out[k-12] (complete, bias folded)
        float y  = own + __builtin_fmaf(sel, ip, xb);
        float e2 = EXP2F(y);
        float rn = __builtin_amdgcn_rcpf(e2 + 1.0f);
        ip = __int_as_float(__builtin_amdgcn_ds_bpermute(bidx, __float_as_int(S)));
        return rn;
    };

    // ---- warm-up ticks 0..11: layer l's r updates only from tick 3l ----
    #pragma unroll
    for (int k = 0; k < WARM; ++k) {
        float dummy;
        float xb = __builtin_fmaf(wx2, xs[k], xconst);
        float rn = (k & 1) ? tick(ipB, xb, dummy) : tick(ipA, xb, dummy);
        r = (k >= 3 * l) ? rn : r;
    }

    // ---- main: ticks 12..2059, tick k emits out[k-12] via row0's import ----
    const float4* xsv = (const float4*)xs;
    for (int kb = WARM; kb <= 2056; kb += 4) {
        float4 xq = xsv[kb >> 2];   // xs[kb..kb+3]; zero-padded past T_LEN
        float ov0, ov1, ov2, ov3;
        r = tick(ipA, __builtin_fmaf(wx2, xq.x, xconst), ov0);
        r = tick(ipB, __builtin_fmaf(wx2, xq.y, xconst), ov1);
        r = tick(ipA, __builtin_fmaf(wx2, xq.z, xconst), ov2);
        r = tick(ipB, __builtin_fmaf(wx2, xq.w, xconst), ov3);
        if (lane == 0)
            *(float4*)(out + (kb - WARM)) = make_float4(ov0, ov1, ov2, ov3);
    }
}

extern "C" void kernel_launch(void* const* d_in, const int* in_sizes, int n_in,
                              void* d_out, int out_size, void* d_ws, size_t ws_size,
                              hipStream_t stream) {
    const float* x     = (const float*)d_in[0];
    const float* h0    = (const float*)d_in[1];
    const float* w_ih0 = (const float*)d_in[2];
    const float* w_ih  = (const float*)d_in[3];
    const float* w_hh  = (const float*)d_in[4];
    const float* b_ih  = (const float*)d_in[5];
    const float* b_hh  = (const float*)d_in[6];
    const float* w_lin = (const float*)d_in[7];
    const float* b_lin = (const float*)d_in[8];
    float* out = (float*)d_out;

    rnn_sig<<<dim3(1), dim3(64), 0, stream>>>(
        x, h0, w_ih0, w_ih, w_hh, b_ih, b_hh, w_lin, b_lin, out);
}